// Round 1
// baseline (122.513 us; speedup 1.0000x reference)
//
#include <hip/hip_runtime.h>

#define DEV __device__ __forceinline__

constexpr int W_  = 4000;  // wavelengths
constexpr int A_  = 64;    // angles
constexpr int M_  = 6;     // fixed materials
constexpr int D_  = 500;   // grid points / padded smooth length
constexpr int NS_ = 331;   // N_SMOOTH
constexpr int KS_ = 20;    // gaussian kernel taps
constexpr int L_  = 22;    // layers
constexpr int ND_ = 20;    // interior layers (thickness count)
constexpr float PIF = 3.14159265358979323846f;

struct cplx { float re, im; };

DEV cplx cmul(cplx a, cplx b) { return { a.re*b.re - a.im*b.im, a.re*b.im + a.im*b.re }; }
DEV cplx cadd(cplx a, cplx b) { return { a.re + b.re, a.im + b.im }; }
DEV cplx csub(cplx a, cplx b) { return { a.re - b.re, a.im - b.im }; }

// naive complex divide — safe when |b| is moderate (f-values are O(1))
DEV cplx cdiv_n(cplx a, cplx b) {
  float d   = fmaf(b.re, b.re, b.im * b.im);
  float inv = 1.0f / d;
  return { fmaf(a.re, b.re,  a.im * b.im) * inv,
           fmaf(a.im, b.re, -a.re * b.im) * inv };
}

// Smith's algorithm — overflow-safe for huge |b| (transfer-matrix entries)
DEV cplx cdiv_s(cplx a, cplx b) {
  bool swap = fabsf(b.im) > fabsf(b.re);
  float bl = swap ? b.im : b.re;   // large component
  float bs = swap ? b.re : b.im;   // small component
  float t   = bs / bl;
  float den = fmaf(bs, t, bl);
  float inv = 1.0f / den;
  float re = swap ? fmaf(a.re, t,  a.im) : fmaf(a.im, t,  a.re);
  float im = swap ? fmaf(a.im, t, -a.re) : fmaf(-a.re, t, a.im);
  return { re * inv, im * inv };
}

// stable principal-branch complex sqrt (branchless)
DEV cplx csqrtc(cplx z) {
  float x = z.re, y = z.im;
  float mag = sqrtf(fmaf(x, x, y * y));
  float t   = sqrtf(0.5f * (mag + fabsf(x)));  // > 0 unless z == 0
  float q   = y / (2.0f * t);
  bool pos  = (x >= 0.0f);
  float re  = pos ? t : fabsf(q);
  float im  = pos ? q : copysignf(t, y);
  return { re, im };
}

// ---------------------------------------------------------------------------
// Kernel 1: wavelength-only preprocessing.
// Computes n_mat[(M+1)][W] (complex, split re/im) into workspace:
//   rows 0..M-1 : interp of fixed material n/k tables onto wavelengths
//   row  M      : interp of gaussian-smoothed unknown curve (imag = 0)
// Mirrors jnp.interp semantics: searchsorted(side='right'), clip to [1,n-1],
// dx==0 -> fp[i], plus out-of-range clamps.
// ---------------------------------------------------------------------------
__global__ __launch_bounds__(256) void precompute_kernel(
    const float* __restrict__ ri,     // [350]
    const float* __restrict__ fixed,  // [M][3][D]
    const float* __restrict__ wl,     // [W]
    float* __restrict__ nre,          // [M+1][W]
    float* __restrict__ nim)
{
  __shared__ float g[KS_];
  __shared__ float nk[D_];
  __shared__ float dyn[D_];
  __shared__ float sgrid[D_];
  __shared__ float red[256];
  int tid = threadIdx.x;

  // gaussian kernel (one thread; trivial)
  if (tid == 0) {
    float step = 20.0f / 19.0f;
    float gv[KS_];
    float s = 0.0f;
    #pragma unroll
    for (int i = 0; i < KS_; ++i) {
      float x  = -10.0f + (float)i * step;
      float xs = x * 0.25f;                 // x / SIGMA (SIGMA = 4)
      float e  = 0.5f * expf(-0.5f * xs * xs);
      gv[i] = e; s += e;
    }
    #pragma unroll
    for (int i = 0; i < KS_; ++i) g[i] = gv[i] / s;
  }

  // grid -> LDS (fixed_data[0][0][:], identical across materials)
  for (int i = tid; i < D_; i += 256) sgrid[i] = fixed[i];

  // min/max of wavelengths
  float lmin = 3.0e38f, lmax = -3.0e38f;
  for (int i = tid; i < W_; i += 256) {
    float v = wl[i];
    lmin = fminf(lmin, v); lmax = fmaxf(lmax, v);
  }
  red[tid] = lmin; __syncthreads();
  for (int s2 = 128; s2 > 0; s2 >>= 1) {
    if (tid < s2) red[tid] = fminf(red[tid], red[tid + s2]);
    __syncthreads();
  }
  float wmin = red[0]; __syncthreads();
  red[tid] = lmax; __syncthreads();
  for (int s2 = 128; s2 > 0; s2 >>= 1) {
    if (tid < s2) red[tid] = fmaxf(red[tid], red[tid + s2]);
    __syncthreads();
  }
  float wmax = red[0];
  __syncthreads();

  // smoothed curve, padded with its last value: nk[k], k in [0, D)
  // convolve(a, g, 'valid')[k] = sum_m a[k+m] * g[KS-1-m]
  for (int k = tid; k < D_; k += 256) {
    int kk = min(k, NS_ - 1);
    float acc = 0.0f;
    #pragma unroll
    for (int m = 0; m < KS_; ++m) acc = fmaf(ri[kk + m], g[KS_ - 1 - m], acc);
    nk[k] = acc;
  }
  // dyn_wl = linspace(wmin, wmax, NS) padded with its last value
  float stepd = (wmax - wmin) / (float)(NS_ - 1);
  for (int i = tid; i < D_; i += 256) {
    int ii = min(i, NS_ - 1);
    dyn[i] = wmin + (float)ii * stepd;
  }
  __syncthreads();

  for (int w = blockIdx.x * 256 + tid; w < W_; w += gridDim.x * 256) {
    float x = wl[w];

    // ---- fixed materials: searchsorted-right on sgrid ----
    int lo = 0, hi = D_;
    while (lo < hi) {
      int mid = (lo + hi) >> 1;
      if (sgrid[mid] <= x) lo = mid + 1; else hi = mid;
    }
    int i = min(max(lo, 1), D_ - 1);
    float x0 = sgrid[i - 1];
    float fr = (x - x0) / (sgrid[i] - x0);
    bool lowc  = (x < sgrid[0]);
    bool highc = (x > sgrid[D_ - 1]);
    for (int m = 0; m < M_; ++m) {
      const float* nptr = fixed + (m * 3 + 1) * D_;
      const float* kptr = fixed + (m * 3 + 2) * D_;
      float nv = fmaf(fr, nptr[i] - nptr[i - 1], nptr[i - 1]);
      float kv = fmaf(fr, kptr[i] - kptr[i - 1], kptr[i - 1]);
      if (lowc)  { nv = nptr[0];      kv = kptr[0]; }
      if (highc) { nv = nptr[D_ - 1]; kv = kptr[D_ - 1]; }
      nre[m * W_ + w] = nv;
      nim[m * W_ + w] = kv;
    }

    // ---- unknown material: searchsorted-right on dyn (has flat tail) ----
    int lo2 = 0, hi2 = D_;
    while (lo2 < hi2) {
      int mid = (lo2 + hi2) >> 1;
      if (dyn[mid] <= x) lo2 = mid + 1; else hi2 = mid;
    }
    int j = min(max(lo2, 1), D_ - 1);
    float dxd = dyn[j] - dyn[j - 1];
    float f;
    if (dxd == 0.0f) f = nk[j];
    else             f = fmaf((x - dyn[j - 1]) / dxd, nk[j] - nk[j - 1], nk[j - 1]);
    if (x < dyn[0])      f = nk[0];
    if (x > dyn[D_ - 1]) f = nk[D_ - 1];
    nre[M_ * W_ + w] = f;
    nim[M_ * W_ + w] = 0.0f;
  }
}

// ---------------------------------------------------------------------------
// Kernel 2: transfer-matrix scan, one thread per (angle, wavelength).
// s-polarization (reference is traced with polarization == 0).
// ---------------------------------------------------------------------------
__global__ __launch_bounds__(256) void tmm_kernel(
    const float* __restrict__ nre, const float* __restrict__ nim,
    const float* __restrict__ wl,  const float* __restrict__ ang,
    const int*   __restrict__ md,  const float* __restrict__ tha,
    const float* __restrict__ thb, const float* __restrict__ unk,
    const float* __restrict__ comp, float* __restrict__ out)
{
  __shared__ int   smd[L_];
  __shared__ float sd[ND_];
  int tid = threadIdx.x;
  if (tid < L_) smd[tid] = md[tid];
  if (tid < 10)            sd[tid] = tha[tid];
  else if (tid == 10)      sd[10]  = unk[0] / 1000.0f * comp[0];
  else if (tid < ND_)      sd[tid] = thb[tid - 11];
  __syncthreads();

  int idx = blockIdx.x * 256 + tid;          // grid is exactly A*W/256 blocks
  int a = idx / W_;
  int w = idx - a * W_;

  float lam  = wl[w];
  float th0  = ang[a] * (PIF / 180.0f);
  float s0   = sinf(th0);
  float klam = 2.0f * PIF / lam;

  int  m0 = smd[0];
  cplx n0 = { nre[m0 * W_ + w], nim[m0 * W_ + w] };
  cplx sin0 = { n0.re * s0, n0.im * s0 };

  // layer 0
  cplx st  = cdiv_n(sin0, n0);
  cplx st2 = cmul(st, st);
  cplx ct  = csqrtc({1.0f - st2.re, -st2.im});
  cplx fpv = cmul(n0, ct);                  // f of previous layer
  cplx f0  = fpv;
  cplx kzp = { fpv.re * klam, fpv.im * klam };

  cplx m00 = {0,0}, m01 = {0,0}, m10 = {0,0}, m11 = {0,0};

  for (int l = 1; l < L_; ++l) {
    int  mm = smd[l];
    cplx nl  = { nre[mm * W_ + w], nim[mm * W_ + w] };
    cplx stl  = cdiv_n(sin0, nl);
    cplx st2l = cmul(stl, stl);
    cplx ctl  = csqrtc({1.0f - st2l.re, -st2l.im});
    cplx fc   = cmul(nl, ctl);

    // interface (l-1, l)
    cplx sum = cadd(fpv, fc);
    cplx dif = csub(fpv, fc);
    cplx r   = cdiv_n(dif, sum);
    cplx two_fp = { 2.0f * fpv.re, 2.0f * fpv.im };
    cplx tinv   = cdiv_n(sum, two_fp);      // 1 / t

    if (l == 1) {
      m00 = tinv; m01 = cmul(r, tinv); m10 = m01; m11 = m00;
    } else {
      // propagate through layer l-1 (delta = kz_{l-1} * d[l-2]), then interface l-1
      float dth = sd[l - 2];
      float dr = kzp.re * dth, di = kzp.im * dth;
      float e1 = expf(di);                  // magnitude of exp(-i*delta)
      float e2 = expf(-di);                 // magnitude of exp(+i*delta)
      float sn, cs;
      sincosf(dr, &sn, &cs);
      cplx em = { e1 * cs, -e1 * sn };      // exp(-i*delta)
      cplx ep = { e2 * cs,  e2 * sn };      // exp(+i*delta)
      cplx aem = cmul(em, tinv);            // a  = exp(-i d)/t
      cplx aep = cmul(ep, tinv);            // dd = exp(+i d)/t
      cplx bb  = cmul(r, aem);              // b  = r*exp(-i d)/t
      cplx cc  = cmul(r, aep);              // c  = r*exp(+i d)/t
      cplx t00 = cadd(cmul(m00, aem), cmul(m01, cc));
      cplx t01 = cadd(cmul(m00, bb),  cmul(m01, aep));
      cplx t10 = cadd(cmul(m10, aem), cmul(m11, cc));
      cplx t11 = cadd(cmul(m10, bb),  cmul(m11, aep));
      m00 = t00; m01 = t01; m10 = t10; m11 = t11;
    }
    fpv = fc;
    kzp = { fc.re * klam, fc.im * klam };
  }

  cplx rr = cdiv_s(m10, m00);               // overflow-safe: |m00| can be ~e^100
  cplx tt = cdiv_s({1.0f, 0.0f}, m00);
  float R = fmaf(rr.re, rr.re, rr.im * rr.im);
  float T = fmaf(tt.re, tt.re, tt.im * tt.im) * fpv.re / f0.re;
  float Aab = 1.0f - R - T;
  out[idx]              = R;
  out[A_ * W_ + idx]    = T;
  out[2 * A_ * W_ + idx] = Aab;
}

extern "C" void kernel_launch(void* const* d_in, const int* in_sizes, int n_in,
                              void* d_out, int out_size, void* d_ws, size_t ws_size,
                              hipStream_t stream) {
  const float* ri    = (const float*)d_in[0];   // refractive_index [350]
  const float* comp  = (const float*)d_in[1];   // compression_ratio [1]
  const float* fixed = (const float*)d_in[2];   // fixed_data [6][3][500]
  const float* tha   = (const float*)d_in[3];   // thickness_above_unk [10]
  const float* thb   = (const float*)d_in[4];   // thickness_below_unk [9]
  const float* wl    = (const float*)d_in[5];   // wavelengths [4000]
  const float* ang   = (const float*)d_in[6];   // angle_of_incidences [64]
  const int*   md    = (const int*)d_in[7];     // material_distribution [22]
  // d_in[8] = polarization (always 0 in this problem's setup)
  const float* unk   = (const float*)d_in[9];   // unknown_layer_thickness [1]
  float* out = (float*)d_out;

  float* nre = (float*)d_ws;                    // [(M+1)][W]
  float* nim = nre + (M_ + 1) * W_;             // [(M+1)][W]  (total 224 KB)

  precompute_kernel<<<16, 256, 0, stream>>>(ri, fixed, wl, nre, nim);
  tmm_kernel<<<(A_ * W_) / 256, 256, 0, stream>>>(nre, nim, wl, ang, md, tha,
                                                  thb, unk, comp, out);
}

// Round 2
// 97.627 us; speedup vs baseline: 1.2549x; 1.2549x over previous
//
#include <hip/hip_runtime.h>

#define DEV __device__ __forceinline__
#define RCP(x)  __builtin_amdgcn_rcpf(x)
#define SQRT(x) __builtin_amdgcn_sqrtf(x)

constexpr int W_  = 4000;  // wavelengths
constexpr int A_  = 64;    // angles
constexpr int D_  = 500;   // grid points / padded length
constexpr int NS_ = 331;   // N_SMOOTH
constexpr int KS_ = 20;    // gaussian taps
constexpr int L_  = 22;    // layers
constexpr float PIF = 3.14159265358979323846f;

struct cplx { float re, im; };

DEV cplx cmul(cplx a, cplx b) { return { a.re*b.re - a.im*b.im, a.re*b.im + a.im*b.re }; }
DEV cplx cadd(cplx a, cplx b) { return { a.re + b.re, a.im + b.im }; }

// Smith's algorithm — overflow-safe for huge |b| (|m00| can be ~e^80)
DEV cplx cdiv_s(cplx a, cplx b) {
  bool swap = fabsf(b.im) > fabsf(b.re);
  float bl = swap ? b.im : b.re;
  float bs = swap ? b.re : b.im;
  float t   = bs / bl;
  float den = fmaf(bs, t, bl);
  float inv = 1.0f / den;
  float re = swap ? fmaf(a.re, t,  a.im) : fmaf(a.im, t,  a.re);
  float im = swap ? fmaf(a.im, t, -a.re) : fmaf(-a.re, t, a.im);
  return { re * inv, im * inv };
}

// stable principal-branch complex sqrt (branchless)
DEV cplx csqrtc(cplx z) {
  float x = z.re, y = z.im;
  float mag = SQRT(fmaf(x, x, y * y));
  float t   = SQRT(0.5f * (mag + fabsf(x)));   // > 0 unless z == 0
  float q   = y * 0.5f * RCP(t);
  bool pos  = (x >= 0.0f);
  float re  = pos ? t : fabsf(q);
  float im  = pos ? q : copysignf(t, y);
  return { re, im };
}

// ---------------------------------------------------------------------------
// Fully fused: per-block interp setup (cheap, ~15% of body) + per-thread TMM.
// One thread = one (angle, wavelength). s-polarization (polarization == 0).
// f-values for the 7 materials live in LDS [m][tid] — each thread touches only
// its own column, so no __syncthreads is needed around them, and the dynamic
// f[md[l]] index stays in LDS instead of spilling to scratch (rule #20).
// ---------------------------------------------------------------------------
__global__ __launch_bounds__(256) void tmm_fused_kernel(
    const float* __restrict__ ri,     // [350]
    const float* __restrict__ comp,   // [1]
    const float* __restrict__ fixed,  // [6][3][500]
    const float* __restrict__ tha,    // [10]
    const float* __restrict__ thb,    // [9]
    const float* __restrict__ wl,     // [4000]
    const float* __restrict__ ang,    // [64]
    const int*   __restrict__ md,     // [22]
    const float* __restrict__ unk,    // [1]
    float* __restrict__ out)          // [3][64][4000]
{
  __shared__ float  s_grid[D_];
  __shared__ float  s_ri[350];
  __shared__ float  s_g[KS_];
  __shared__ int    s_md[L_];
  __shared__ float  s_d[20];
  __shared__ float  s_mn[4], s_mx[4];
  __shared__ float2 s_f[7 * 256];     // per-thread-column material scratch (14 KB)

  const int tid = threadIdx.x;

  // ---- stage small tables ----
  for (int i = tid; i < D_;  i += 256) s_grid[i] = fixed[i];   // fixed[0][0][:]
  for (int i = tid; i < 350; i += 256) s_ri[i]   = ri[i];
  if (tid < KS_) {
    float x  = -10.0f + (float)tid * (20.0f / 19.0f);
    float xs = x * 0.25f;                         // x / SIGMA
    s_g[tid] = 0.5f * expf(-0.5f * xs * xs);      // unnormalized; scale later
  }
  if (tid < L_) s_md[tid] = md[tid];
  if (tid < 20)
    s_d[tid] = (tid < 10) ? tha[tid]
             : (tid == 10 ? unk[0] / 1000.0f * comp[0] : thb[tid - 11]);

  // ---- block-level min/max of wavelengths (matches jnp.min/jnp.max) ----
  float lmin = 3.4e38f, lmax = -3.4e38f;
  for (int i = tid; i < W_; i += 256) {
    float v = wl[i];
    lmin = fminf(lmin, v); lmax = fmaxf(lmax, v);
  }
  #pragma unroll
  for (int o = 32; o; o >>= 1) {
    lmin = fminf(lmin, __shfl_xor(lmin, o, 64));
    lmax = fmaxf(lmax, __shfl_xor(lmax, o, 64));
  }
  if ((tid & 63) == 0) { s_mn[tid >> 6] = lmin; s_mx[tid >> 6] = lmax; }
  __syncthreads();
  const float wmin = fminf(fminf(s_mn[0], s_mn[1]), fminf(s_mn[2], s_mn[3]));
  const float wmax = fmaxf(fmaxf(s_mx[0], s_mx[1]), fmaxf(s_mx[2], s_mx[3]));

  // ---- this thread's (a, w) ----
  const int a  = blockIdx.y;
  const int w  = blockIdx.x * 256 + tid;          // 16*256 = 4096 covers W
  const int wc = min(w, W_ - 1);
  const float x = wl[wc];

  // ---- fixed materials: searchsorted-right on s_grid ----
  int lo = 0, hi = D_;
  while (lo < hi) { int mid = (lo + hi) >> 1; if (s_grid[mid] <= x) lo = mid + 1; else hi = mid; }
  const int i = min(max(lo, 1), D_ - 1);
  const float gx0 = s_grid[i - 1];
  const float fr  = (x - gx0) * RCP(s_grid[i] - gx0);
  const bool lowc  = (x < s_grid[0]);
  const bool highc = (x > s_grid[D_ - 1]);

  #pragma unroll
  for (int m = 0; m < 6; ++m) {
    const float* nptr = fixed + (m * 3 + 1) * D_;
    const float* kptr = fixed + (m * 3 + 2) * D_;
    float nv = fmaf(fr, nptr[i] - nptr[i - 1], nptr[i - 1]);
    float kv = fmaf(fr, kptr[i] - kptr[i - 1], kptr[i - 1]);
    if (lowc)  { nv = nptr[0];      kv = kptr[0]; }
    if (highc) { nv = nptr[D_ - 1]; kv = kptr[D_ - 1]; }
    s_f[m * 256 + tid] = make_float2(nv, kv);
  }

  // ---- unknown material: uniform-grid interp of smoothed curve ----
  {
    float gsum = 0.0f;
    #pragma unroll
    for (int k = 0; k < KS_; ++k) gsum += s_g[k];
    const float ginv  = 1.0f / gsum;
    const float stepd = (wmax - wmin) / (float)(NS_ - 1);
    const float istep = RCP(stepd);
    int j = (int)floorf((x - wmin) * istep) + 1;
    j = min(max(j, 1), NS_ - 1);
    const int j0 = j - 1;
    float a0 = 0.0f, a1 = 0.0f;
    #pragma unroll
    for (int k = 0; k < KS_; ++k) {
      const float gk = s_g[KS_ - 1 - k];
      a0 = fmaf(s_ri[j0 + k], gk, a0);
      a1 = fmaf(s_ri[j0 + 1 + k], gk, a1);
    }
    a0 *= ginv; a1 *= ginv;
    const float d0 = fmaf((float)j0, stepd, wmin);
    const float d1 = fmaf((float)j,  stepd, wmin);
    const float f  = fmaf((x - d0) * RCP(d1 - d0), a1 - a0, a0);
    s_f[6 * 256 + tid] = make_float2(f, 0.0f);
  }

  // ---- per-thread angle setup ----
  const float th0  = ang[a] * (PIF / 180.0f);
  const float s0   = sinf(th0);
  const float klam = 2.0f * PIF * RCP(x);

  const int md0 = s_md[0];
  const float2 nn0 = s_f[md0 * 256 + tid];
  const cplx sin0 = { nn0.x * s0, nn0.y * s0 };

  // ---- n -> f = n*cos(theta) for each of the 7 materials (dedup!) ----
  #pragma unroll
  for (int m = 0; m < 7; ++m) {
    const float2 nn = s_f[m * 256 + tid];
    const float ind = RCP(fmaf(nn.x, nn.x, nn.y * nn.y));
    const cplx invn = { nn.x * ind, -nn.y * ind };
    const cplx st   = cmul(sin0, invn);
    const cplx st2  = cmul(st, st);
    const cplx ct   = csqrtc({ 1.0f - st2.re, -st2.im });
    const cplx f    = cmul({ nn.x, nn.y }, ct);
    s_f[m * 256 + tid] = make_float2(f.re, f.im);
  }

  const float2 f0v = s_f[md0 * 256 + tid];
  const cplx f0 = { f0v.x, f0v.y };

  // ---- transfer-matrix scan, q-form interfaces ----
  cplx m00 = {0,0}, m01 = {0,0}, m10 = {0,0}, m11 = {0,0};
  cplx fp = f0;
  {
    // nothing
  }
  float id0 = RCP(fmaf(fp.re, fp.re, fp.im * fp.im));
  cplx ifp = { fp.re * id0, -fp.im * id0 };

  #pragma unroll
  for (int l = 1; l < L_; ++l) {
    const float2 fcv = s_f[s_md[l] * 256 + tid];
    const cplx fc = { fcv.x, fcv.y };
    const cplx q  = cmul(fc, ifp);                 // fc / fp
    const cplx opq = { 1.0f + q.re,  q.im };       // 1 + q
    const cplx tinv = { 0.5f * opq.re, 0.5f * opq.im };   // (1+q)/2 = 1/t
    const float idq = RCP(fmaf(opq.re, opq.re, opq.im * opq.im));
    const cplx omq = { 1.0f - q.re, -q.im };       // 1 - q
    const cplx r = { fmaf(omq.re, opq.re,  omq.im * opq.im) * idq,
                     fmaf(omq.im, opq.re, -omq.re * opq.im) * idq };

    if (l == 1) {
      m00 = tinv; m01 = cmul(r, tinv); m10 = m01; m11 = tinv;
    } else {
      const float cst = klam * s_d[l - 2];
      const float dr = fp.re * cst, di = fp.im * cst;
      const float e1 = __expf(di);
      const float e2 = RCP(e1);
      float sn, cs;
      __sincosf(dr, &sn, &cs);
      const cplx em = { e1 * cs, -e1 * sn };       // exp(-i*delta)
      const cplx ep = { e2 * cs,  e2 * sn };       // exp(+i*delta)
      const cplx aem = cmul(em, tinv);
      const cplx aep = cmul(ep, tinv);
      const cplx bb  = cmul(r, aem);
      const cplx cc  = cmul(r, aep);
      const cplx t00 = cadd(cmul(m00, aem), cmul(m01, cc));
      const cplx t01 = cadd(cmul(m00, bb),  cmul(m01, aep));
      const cplx t10 = cadd(cmul(m10, aem), cmul(m11, cc));
      const cplx t11 = cadd(cmul(m10, bb),  cmul(m11, aep));
      m00 = t00; m01 = t01; m10 = t10; m11 = t11;
    }
    fp = fc;
    const float idd = RCP(fmaf(fc.re, fc.re, fc.im * fc.im));
    ifp = { fc.re * idd, -fc.im * idd };
  }

  // ---- outputs ----
  const cplx rr = cdiv_s(m10, m00);
  const cplx tt = cdiv_s({1.0f, 0.0f}, m00);
  const float R = fmaf(rr.re, rr.re, rr.im * rr.im);
  const float T = fmaf(tt.re, tt.re, tt.im * tt.im) * fp.re / f0.re;

  if (w < W_) {
    const int o = a * W_ + w;
    out[o]             = R;
    out[A_ * W_ + o]   = T;
    out[2 * A_ * W_ + o] = 1.0f - R - T;
  }
}

extern "C" void kernel_launch(void* const* d_in, const int* in_sizes, int n_in,
                              void* d_out, int out_size, void* d_ws, size_t ws_size,
                              hipStream_t stream) {
  const float* ri    = (const float*)d_in[0];
  const float* comp  = (const float*)d_in[1];
  const float* fixed = (const float*)d_in[2];
  const float* tha   = (const float*)d_in[3];
  const float* thb   = (const float*)d_in[4];
  const float* wl    = (const float*)d_in[5];
  const float* ang   = (const float*)d_in[6];
  const int*   md    = (const int*)d_in[7];
  // d_in[8] = polarization (0)
  const float* unk   = (const float*)d_in[9];
  float* out = (float*)d_out;

  dim3 grid(16, A_);   // 16*256 = 4096 >= W, y = angle
  tmm_fused_kernel<<<grid, 256, 0, stream>>>(ri, comp, fixed, tha, thb, wl,
                                             ang, md, unk, out);
}

// Round 4
// 97.367 us; speedup vs baseline: 1.2583x; 1.0027x over previous
//
#include <hip/hip_runtime.h>

#define DEV __device__ __forceinline__
#define RCP(x)  __builtin_amdgcn_rcpf(x)
#define SQRT(x) __builtin_amdgcn_sqrtf(x)

constexpr int W_  = 4000;  // wavelengths
constexpr int A_  = 64;    // angles
constexpr int D_  = 500;   // grid points / padded length
constexpr int NS_ = 331;   // N_SMOOTH
constexpr int KS_ = 20;    // gaussian taps
constexpr int L_  = 22;    // layers
constexpr float PIF = 3.14159265358979323846f;

struct cplx { float re, im; };

DEV cplx cmul(cplx a, cplx b) { return { a.re*b.re - a.im*b.im, a.re*b.im + a.im*b.re }; }
// fast complex inverse (rcp-based; |z| is O(1) everywhere it's used)
DEV cplx cinv(cplx z) {
  float d = RCP(fmaf(z.re, z.re, z.im * z.im));
  return { z.re * d, -z.im * d };
}

// stable principal-branch complex sqrt (branchless)
DEV cplx csqrtc(cplx z) {
  float x = z.re, y = z.im;
  float mag = SQRT(fmaf(x, x, y * y));
  float t   = SQRT(0.5f * (mag + fabsf(x)));   // > 0 unless z == 0
  float q   = y * 0.5f * RCP(t);
  bool pos  = (x >= 0.0f);
  float re  = pos ? t : fabsf(q);
  float im  = pos ? q : copysignf(t, y);
  return { re, im };
}

// ---------------------------------------------------------------------------
// Fully fused TMM via Parratt backward recursion.
// One thread = one (angle, wavelength); s-polarization (polarization == 0).
// Per-material f = n*cos(theta) AND 1/f live in LDS float4 [m][tid] — each
// thread owns its column (no syncs, dynamic md[] index stays in LDS, rule #20).
// Backward scan: u <- e^{2i delta}(r+u)/(1+ru); tt accumulates t e^{i delta}
// over the shared denominator; no overflow (all factors bounded <= O(1)).
// ---------------------------------------------------------------------------
__global__ __launch_bounds__(256) void tmm_fused_kernel(
    const float* __restrict__ ri,     // [350]
    const float* __restrict__ comp,   // [1]
    const float* __restrict__ fixed,  // [6][3][500]
    const float* __restrict__ tha,    // [10]
    const float* __restrict__ thb,    // [9]
    const float* __restrict__ wl,     // [4000]
    const float* __restrict__ ang,    // [64]
    const int*   __restrict__ md,     // [22]
    const float* __restrict__ unk,    // [1]
    float* __restrict__ out)          // [3][64][4000]
{
  __shared__ float  s_grid[D_];
  __shared__ float  s_ri[350];
  __shared__ float  s_g[KS_];
  __shared__ int    s_md[L_];
  __shared__ float  s_d[20];
  __shared__ float  s_mn[4], s_mx[4];
  __shared__ float4 s_f[7 * 256];     // (f.re, f.im, invf.re, invf.im)  28 KB

  const int tid = threadIdx.x;

  // ---- stage small tables ----
  for (int i = tid; i < D_;  i += 256) s_grid[i] = fixed[i];   // fixed[0][0][:]
  for (int i = tid; i < 350; i += 256) s_ri[i]   = ri[i];
  if (tid < KS_) {
    float x  = -10.0f + (float)tid * (20.0f / 19.0f);
    float xs = x * 0.25f;                         // x / SIGMA
    s_g[tid] = 0.5f * expf(-0.5f * xs * xs);      // unnormalized; scale later
  }
  if (tid < L_) s_md[tid] = md[tid];
  if (tid < 20)
    s_d[tid] = (tid < 10) ? tha[tid]
             : (tid == 10 ? unk[0] / 1000.0f * comp[0] : thb[tid - 11]);

  // ---- block-level min/max of wavelengths (matches jnp.min/jnp.max) ----
  float lmin = 3.4e38f, lmax = -3.4e38f;
  for (int i = tid; i < W_; i += 256) {
    float v = wl[i];
    lmin = fminf(lmin, v); lmax = fmaxf(lmax, v);
  }
  #pragma unroll
  for (int o = 32; o; o >>= 1) {
    lmin = fminf(lmin, __shfl_xor(lmin, o, 64));
    lmax = fmaxf(lmax, __shfl_xor(lmax, o, 64));
  }
  if ((tid & 63) == 0) { s_mn[tid >> 6] = lmin; s_mx[tid >> 6] = lmax; }
  __syncthreads();
  const float wmin = fminf(fminf(s_mn[0], s_mn[1]), fminf(s_mn[2], s_mn[3]));
  const float wmax = fmaxf(fmaxf(s_mx[0], s_mx[1]), fmaxf(s_mx[2], s_mx[3]));

  // ---- this thread's (a, w) ----
  const int a  = blockIdx.y;
  const int w  = blockIdx.x * 256 + tid;          // 16*256 = 4096 covers W
  const int wc = min(w, W_ - 1);
  const float x = wl[wc];

  // ---- fixed materials: searchsorted-right on s_grid ----
  int lo = 0, hi = D_;
  while (lo < hi) { int mid = (lo + hi) >> 1; if (s_grid[mid] <= x) lo = mid + 1; else hi = mid; }
  const int i = min(max(lo, 1), D_ - 1);
  const float gx0 = s_grid[i - 1];
  const float fr  = (x - gx0) * RCP(s_grid[i] - gx0);
  const bool lowc  = (x < s_grid[0]);
  const bool highc = (x > s_grid[D_ - 1]);

  #pragma unroll
  for (int m = 0; m < 6; ++m) {
    const float* nptr = fixed + (m * 3 + 1) * D_;
    const float* kptr = fixed + (m * 3 + 2) * D_;
    float nv = fmaf(fr, nptr[i] - nptr[i - 1], nptr[i - 1]);
    float kv = fmaf(fr, kptr[i] - kptr[i - 1], kptr[i - 1]);
    if (lowc)  { nv = nptr[0];      kv = kptr[0]; }
    if (highc) { nv = nptr[D_ - 1]; kv = kptr[D_ - 1]; }
    s_f[m * 256 + tid] = make_float4(nv, kv, 0.0f, 0.0f);
  }

  // ---- unknown material: uniform-grid interp of smoothed curve ----
  {
    float gsum = 0.0f;
    #pragma unroll
    for (int k = 0; k < KS_; ++k) gsum += s_g[k];
    const float ginv  = 1.0f / gsum;
    const float stepd = (wmax - wmin) / (float)(NS_ - 1);
    const float istep = RCP(stepd);
    int j = (int)floorf((x - wmin) * istep) + 1;
    j = min(max(j, 1), NS_ - 1);
    const int j0 = j - 1;
    float a0 = 0.0f, a1 = 0.0f;
    #pragma unroll
    for (int k = 0; k < KS_; ++k) {
      const float gk = s_g[KS_ - 1 - k];
      a0 = fmaf(s_ri[j0 + k], gk, a0);
      a1 = fmaf(s_ri[j0 + 1 + k], gk, a1);
    }
    a0 *= ginv; a1 *= ginv;
    const float d0 = fmaf((float)j0, stepd, wmin);
    const float d1 = fmaf((float)j,  stepd, wmin);
    const float f  = fmaf((x - d0) * RCP(d1 - d0), a1 - a0, a0);
    s_f[6 * 256 + tid] = make_float4(f, 0.0f, 0.0f, 0.0f);
  }

  // ---- per-thread angle setup ----
  const float th0  = ang[a] * (PIF / 180.0f);
  const float s0   = sinf(th0);
  const float klam = 2.0f * PIF * RCP(x);

  const int md0 = s_md[0];
  const float4 nn0 = s_f[md0 * 256 + tid];
  const cplx sin0 = { nn0.x * s0, nn0.y * s0 };

  // ---- n -> (f, 1/f) for each of the 7 materials (dedup) ----
  #pragma unroll
  for (int m = 0; m < 7; ++m) {
    const float4 nn = s_f[m * 256 + tid];
    const cplx invn = cinv({ nn.x, nn.y });
    const cplx st   = cmul(sin0, invn);
    const cplx st2  = cmul(st, st);
    const cplx ct   = csqrtc({ 1.0f - st2.re, -st2.im });
    const cplx f    = cmul({ nn.x, nn.y }, ct);
    const cplx fi   = cinv(f);
    s_f[m * 256 + tid] = make_float4(f.re, f.im, fi.re, fi.im);
  }

  // ---- Parratt backward recursion over interfaces j = 20 .. 1 ----
  // at step j we need layer j (f and 1/f) and layer j+1 (f, carried in fdn).
  cplx u   = { 0.0f, 0.0f };          // u_{j+1}, starts u_21 = 0
  cplx tac = { 1.0f, 0.0f };          // Π (t_j/2) e^{i d_j} / (1 + r_j u_{j+1})
  float4 fdn = s_f[s_md[L_ - 1] * 256 + tid];   // layer j+1 (starts: layer 21)
  const float fL_re = fdn.x;                    // Re f of last layer (for T)

  #pragma unroll
  for (int j = L_ - 2; j >= 1; --j) {
    const float4 fj = s_f[s_md[j] * 256 + tid]; // layer j: (f, 1/f)
    const cplx q   = cmul({ fdn.x, fdn.y }, { fj.z, fj.w });   // f_{j+1}/f_j
    const cplx iop = cinv({ 1.0f + q.re, q.im });
    const cplx r   = cmul({ 1.0f - q.re, -q.im }, iop);        // (1-q)/(1+q)

    // phase of layer j: delta = f_j * klam * d[j-1]
    const float cst = klam * s_d[j - 1];
    const float dr = fj.x * cst, di = fj.y * cst;
    const float e2 = __expf(-di);               // |e^{+i delta}| (decaying)
    float sn, cs;
    __sincosf(dr, &sn, &cs);
    const cplx ph   = { e2 * cs, e2 * sn };     // e^{+i delta}
    const cplx beta = cmul(ph, ph);             // e^{+2i delta}

    const cplx ru  = cmul(r, u);
    const cplx idn = cinv({ 1.0f + ru.re, ru.im });
    // tac *= (t_j/2) e^{i delta} / (1 + r u)   [t_j = 2*iop]
    tac = cmul(tac, cmul(cmul(iop, ph), idn));
    // u <- e^{2i delta} (r + u) / (1 + r u)
    u = cmul(beta, cmul({ r.re + u.re, r.im + u.im }, idn));

    fdn = fj;
  }

  // ---- interface 0 ----
  const float4 f0v = s_f[md0 * 256 + tid];      // layer 0 (f, 1/f)
  const cplx q0   = cmul({ fdn.x, fdn.y }, { f0v.z, f0v.w });  // f_1/f_0
  const cplx iop0 = cinv({ 1.0f + q0.re, q0.im });
  const cplx r0   = cmul({ 1.0f - q0.re, -q0.im }, iop0);
  const cplx ru0  = cmul(r0, u);
  const cplx idn0 = cinv({ 1.0f + ru0.re, ru0.im });
  const cplx rr   = cmul({ r0.re + u.re, r0.im + u.im }, idn0);
  cplx tt = cmul(cmul(iop0, idn0), tac);        // still missing 2^21

  const float SC = 2097152.0f;                  // 2^21 (one 2 per interface)
  tt.re *= SC; tt.im *= SC;

  const float R = fmaf(rr.re, rr.re, rr.im * rr.im);
  const float T = fmaf(tt.re, tt.re, tt.im * tt.im) * fL_re * RCP(f0v.x);

  if (w < W_) {
    const int o = a * W_ + w;
    out[o]               = R;
    out[A_ * W_ + o]     = T;
    out[2 * A_ * W_ + o] = 1.0f - R - T;
  }
}

extern "C" void kernel_launch(void* const* d_in, const int* in_sizes, int n_in,
                              void* d_out, int out_size, void* d_ws, size_t ws_size,
                              hipStream_t stream) {
  const float* ri    = (const float*)d_in[0];
  const float* comp  = (const float*)d_in[1];
  const float* fixed = (const float*)d_in[2];
  const float* tha   = (const float*)d_in[3];
  const float* thb   = (const float*)d_in[4];
  const float* wl    = (const float*)d_in[5];
  const float* ang   = (const float*)d_in[6];
  const int*   md    = (const int*)d_in[7];
  // d_in[8] = polarization (0)
  const float* unk   = (const float*)d_in[9];
  float* out = (float*)d_out;

  dim3 grid(16, A_);   // 16*256 = 4096 >= W, y = angle
  tmm_fused_kernel<<<grid, 256, 0, stream>>>(ri, comp, fixed, tha, thb, wl,
                                             ang, md, unk, out);
}

// Round 6
// 93.045 us; speedup vs baseline: 1.3167x; 1.0465x over previous
//
#include <hip/hip_runtime.h>

#define DEV __device__ __forceinline__
#define RCP(x)  __builtin_amdgcn_rcpf(x)
#define SQRT(x) __builtin_amdgcn_sqrtf(x)

constexpr int W_  = 4000;  // wavelengths
constexpr int A_  = 64;    // angles
constexpr int D_  = 500;   // grid points / padded length
constexpr int NS_ = 331;   // N_SMOOTH
constexpr int KS_ = 20;    // gaussian taps
constexpr int L_  = 22;    // layers
constexpr float PIF = 3.14159265358979323846f;

struct cplx { float re, im; };

DEV cplx cmul(cplx a, cplx b) { return { a.re*b.re - a.im*b.im, a.re*b.im + a.im*b.re }; }
DEV cplx cinv(cplx z) {
  float d = RCP(fmaf(z.re, z.re, z.im * z.im));
  return { z.re * d, -z.im * d };
}
// stable principal-branch complex sqrt (branchless)
DEV cplx csqrtc(cplx z) {
  float x = z.re, y = z.im;
  float mag = SQRT(fmaf(x, x, y * y));
  float t   = SQRT(0.5f * (mag + fabsf(x)));
  float q   = y * 0.5f * RCP(t);
  bool pos  = (x >= 0.0f);
  float re  = pos ? t : fabsf(q);
  float im  = pos ? q : copysignf(t, y);
  return { re, im };
}

// ---------------------------------------------------------------------------
// Kernel A — wavelength-only (16 blocks). For each (material m, wavelength w)
// emits float4( n_m.re, n_m.im, z.re, z.im ) with z = (n0/n_m)^2, so the main
// kernel's angle chain is just csqrtc(1 - s0^2 * z). Duplicating this per
// angle (R2/R4 fused design) cost 64x redundant binary-search + interp with
// serially-dependent LDS reads — the latency-bound part of the old kernel.
// ---------------------------------------------------------------------------
__global__ __launch_bounds__(256) void precompute_kernel(
    const float* __restrict__ ri,     // [350]
    const float* __restrict__ fixed,  // [6][3][500]
    const float* __restrict__ wl,     // [4000]
    const int*   __restrict__ md,     // [22]
    float4* __restrict__ nz)          // [7][W]
{
  __shared__ float s_grid[D_];
  __shared__ float s_ri[350];
  __shared__ float s_g[KS_];
  __shared__ float s_mn[4], s_mx[4];

  const int tid = threadIdx.x;

  for (int i = tid; i < D_;  i += 256) s_grid[i] = fixed[i];   // fixed[0][0][:]
  for (int i = tid; i < 350; i += 256) s_ri[i]   = ri[i];
  if (tid < KS_) {
    float x  = -10.0f + (float)tid * (20.0f / 19.0f);
    float xs = x * 0.25f;                         // x / SIGMA
    s_g[tid] = 0.5f * expf(-0.5f * xs * xs);      // unnormalized; scale later
  }

  // block-level min/max of wavelengths (matches jnp.min/jnp.max)
  float lmin = 3.4e38f, lmax = -3.4e38f;
  for (int i = tid; i < W_; i += 256) {
    float v = wl[i];
    lmin = fminf(lmin, v); lmax = fmaxf(lmax, v);
  }
  #pragma unroll
  for (int o = 32; o; o >>= 1) {
    lmin = fminf(lmin, __shfl_xor(lmin, o, 64));
    lmax = fmaxf(lmax, __shfl_xor(lmax, o, 64));
  }
  if ((tid & 63) == 0) { s_mn[tid >> 6] = lmin; s_mx[tid >> 6] = lmax; }
  __syncthreads();
  const float wmin = fminf(fminf(s_mn[0], s_mn[1]), fminf(s_mn[2], s_mn[3]));
  const float wmax = fmaxf(fmaxf(s_mx[0], s_mx[1]), fmaxf(s_mx[2], s_mx[3]));

  const int w  = blockIdx.x * 256 + tid;          // 16*256 = 4096 covers W
  const int wc = min(w, W_ - 1);
  const float x = wl[wc];

  cplx nm[7];   // registers, all indices compile-time

  // fixed materials: searchsorted-right on s_grid
  int lo = 0, hi = D_;
  while (lo < hi) { int mid = (lo + hi) >> 1; if (s_grid[mid] <= x) lo = mid + 1; else hi = mid; }
  const int i = min(max(lo, 1), D_ - 1);
  const float gx0 = s_grid[i - 1];
  const float fr  = (x - gx0) * RCP(s_grid[i] - gx0);
  const bool lowc  = (x < s_grid[0]);
  const bool highc = (x > s_grid[D_ - 1]);

  #pragma unroll
  for (int m = 0; m < 6; ++m) {
    const float* nptr = fixed + (m * 3 + 1) * D_;
    const float* kptr = fixed + (m * 3 + 2) * D_;
    float nv = fmaf(fr, nptr[i] - nptr[i - 1], nptr[i - 1]);
    float kv = fmaf(fr, kptr[i] - kptr[i - 1], kptr[i - 1]);
    if (lowc)  { nv = nptr[0];      kv = kptr[0]; }
    if (highc) { nv = nptr[D_ - 1]; kv = kptr[D_ - 1]; }
    nm[m] = { nv, kv };
  }

  // unknown material: uniform-grid interp of smoothed curve (proven in R2/R4)
  {
    float gsum = 0.0f;
    #pragma unroll
    for (int k = 0; k < KS_; ++k) gsum += s_g[k];
    const float ginv  = 1.0f / gsum;
    const float stepd = (wmax - wmin) / (float)(NS_ - 1);
    int j = (int)floorf((x - wmin) * RCP(stepd)) + 1;
    j = min(max(j, 1), NS_ - 1);
    const int j0 = j - 1;
    float a0 = 0.0f, a1 = 0.0f;
    #pragma unroll
    for (int k = 0; k < KS_; ++k) {
      const float gk = s_g[KS_ - 1 - k];
      a0 = fmaf(s_ri[j0 + k], gk, a0);
      a1 = fmaf(s_ri[j0 + 1 + k], gk, a1);
    }
    a0 *= ginv; a1 *= ginv;
    const float d0 = fmaf((float)j0, stepd, wmin);
    const float d1 = fmaf((float)j,  stepd, wmin);
    nm[6] = { fmaf((x - d0) * RCP(d1 - d0), a1 - a0, a0), 0.0f };
  }

  // n0 = n of the incidence material (register select chain, uniform md0)
  const int m0 = md[0];
  cplx n0 = nm[0];
  #pragma unroll
  for (int m = 1; m < 7; ++m) if (m0 == m) n0 = nm[m];

  if (w < W_) {
    #pragma unroll
    for (int m = 0; m < 7; ++m) {
      const cplx q = cmul(n0, cinv(nm[m]));   // n0/n_m
      const cplx z = cmul(q, q);              // (n0/n_m)^2
      nz[m * W_ + w] = make_float4(nm[m].re, nm[m].im, z.re, z.im);
    }
  }
}

// ---------------------------------------------------------------------------
// Kernel B — one thread per (angle, wavelength). No barriers, no staged setup:
// 7 coalesced float4 loads + 7 f-chains + Parratt backward scan. md[] and
// thicknesses are uniform scalar loads (compile-time unrolled j). s_f columns
// are per-thread-owned (dynamic material index stays in LDS, rule #20).
// ---------------------------------------------------------------------------
__global__ __launch_bounds__(256) void tmm_kernel(
    const float4* __restrict__ nz,    // [7][W]
    const float*  __restrict__ wl,    // [4000]
    const float*  __restrict__ ang,   // [64]
    const int*    __restrict__ md,    // [22]
    const float*  __restrict__ tha,   // [10]
    const float*  __restrict__ thb,   // [9]
    const float*  __restrict__ unk,   // [1]
    const float*  __restrict__ comp,  // [1]
    float* __restrict__ out)          // [3][64][4000]
{
  __shared__ float4 s_f[7 * 256];     // (f, 1/f) per material per thread; 28 KB

  const int tid = threadIdx.x;
  const int w = blockIdx.x * 256 + tid;
  if (w >= W_) return;
  const int a = blockIdx.y;

  const float th0  = ang[a] * (PIF / 180.0f);
  const float s0   = sinf(th0);
  const float s0sq = s0 * s0;
  const float klam = 2.0f * PIF * RCP(wl[w]);

  // f_m = n_m * cos(theta_m),  cos = csqrt(1 - s0^2 * (n0/n_m)^2)
  #pragma unroll
  for (int m = 0; m < 7; ++m) {
    const float4 v = nz[m * W_ + w];
    const cplx st2 = { v.z * s0sq, v.w * s0sq };
    const cplx ct  = csqrtc({ 1.0f - st2.re, -st2.im });
    const cplx f   = cmul({ v.x, v.y }, ct);
    const cplx fi  = cinv(f);
    s_f[m * 256 + tid] = make_float4(f.re, f.im, fi.re, fi.im);
  }

  // Parratt backward recursion (identical math to R4, which passed)
  cplx u   = { 0.0f, 0.0f };
  cplx tac = { 1.0f, 0.0f };
  float4 fdn = s_f[md[L_ - 1] * 256 + tid];
  const float fL_re = fdn.x;

  #pragma unroll
  for (int j = L_ - 2; j >= 1; --j) {
    const float4 fj = s_f[md[j] * 256 + tid];
    const cplx q   = cmul({ fdn.x, fdn.y }, { fj.z, fj.w });   // f_{j+1}/f_j
    const cplx iop = cinv({ 1.0f + q.re, q.im });
    const cplx r   = cmul({ 1.0f - q.re, -q.im }, iop);        // (1-q)/(1+q)

    // thickness of layer j (compile-time j -> uniform scalar loads)
    const float dthj = (j - 1) < 10 ? tha[j - 1]
                     : ((j - 1) == 10 ? unk[0] / 1000.0f * comp[0]
                                      : thb[j - 12]);
    const float cst = klam * dthj;
    const float dr = fj.x * cst, di = fj.y * cst;
    const float e2 = __expf(-di);               // |e^{+i delta}|
    float sn, cs;
    __sincosf(dr, &sn, &cs);
    const cplx ph   = { e2 * cs, e2 * sn };     // e^{+i delta}
    const cplx beta = cmul(ph, ph);             // e^{+2i delta}

    const cplx ru  = cmul(r, u);
    const cplx idn = cinv({ 1.0f + ru.re, ru.im });
    tac = cmul(tac, cmul(cmul(iop, ph), idn));  // *= (t_j/2) e^{i d}/(1+ru)
    u = cmul(beta, cmul({ r.re + u.re, r.im + u.im }, idn));

    fdn = fj;
  }

  // interface 0
  const float4 f0v = s_f[md[0] * 256 + tid];
  const cplx q0   = cmul({ fdn.x, fdn.y }, { f0v.z, f0v.w });
  const cplx iop0 = cinv({ 1.0f + q0.re, q0.im });
  const cplx r0   = cmul({ 1.0f - q0.re, -q0.im }, iop0);
  const cplx ru0  = cmul(r0, u);
  const cplx idn0 = cinv({ 1.0f + ru0.re, ru0.im });
  const cplx rr   = cmul({ r0.re + u.re, r0.im + u.im }, idn0);
  cplx tt = cmul(cmul(iop0, idn0), tac);

  const float SC = 2097152.0f;                  // 2^21 (one 2 per interface)
  tt.re *= SC; tt.im *= SC;

  const float R = fmaf(rr.re, rr.re, rr.im * rr.im);
  const float T = fmaf(tt.re, tt.re, tt.im * tt.im) * fL_re * RCP(f0v.x);

  const int o = a * W_ + w;
  out[o]               = R;
  out[A_ * W_ + o]     = T;
  out[2 * A_ * W_ + o] = 1.0f - R - T;
}

extern "C" void kernel_launch(void* const* d_in, const int* in_sizes, int n_in,
                              void* d_out, int out_size, void* d_ws, size_t ws_size,
                              hipStream_t stream) {
  const float* ri    = (const float*)d_in[0];
  const float* comp  = (const float*)d_in[1];
  const float* fixed = (const float*)d_in[2];
  const float* tha   = (const float*)d_in[3];
  const float* thb   = (const float*)d_in[4];
  const float* wl    = (const float*)d_in[5];
  const float* ang   = (const float*)d_in[6];
  const int*   md    = (const int*)d_in[7];
  // d_in[8] = polarization (0)
  const float* unk   = (const float*)d_in[9];
  float* out = (float*)d_out;

  float4* nz = (float4*)d_ws;                   // [7][W] = 448 KB

  precompute_kernel<<<16, 256, 0, stream>>>(ri, fixed, wl, md, nz);
  dim3 grid(16, A_);
  tmm_kernel<<<grid, 256, 0, stream>>>(nz, wl, ang, md, tha, thb, unk, comp, out);
}

// Round 11
// 91.791 us; speedup vs baseline: 1.3347x; 1.0137x over previous
//
#include <hip/hip_runtime.h>

#define DEV __device__ __forceinline__
#define RCP(x)  __builtin_amdgcn_rcpf(x)
#define SQRT(x) __builtin_amdgcn_sqrtf(x)

constexpr int W_  = 4000;  // wavelengths
constexpr int A_  = 64;    // angles
constexpr int D_  = 500;   // grid points / padded length
constexpr int NS_ = 331;   // N_SMOOTH
constexpr int KS_ = 20;    // gaussian taps
constexpr int L_  = 22;    // layers
constexpr float PIF = 3.14159265358979323846f;

struct cplx { float re, im; };

DEV cplx cmul(cplx a, cplx b) { return { a.re*b.re - a.im*b.im, a.re*b.im + a.im*b.re }; }
DEV cplx cadd(cplx a, cplx b) { return { a.re + b.re, a.im + b.im }; }
DEV cplx cinv(cplx z) {
  float d = RCP(fmaf(z.re, z.re, z.im * z.im));
  return { z.re * d, -z.im * d };
}
// stable principal-branch complex sqrt (branchless)
DEV cplx csqrtc(cplx z) {
  float x = z.re, y = z.im;
  float mag = SQRT(fmaf(x, x, y * y));
  float t   = SQRT(0.5f * (mag + fabsf(x)));
  float q   = y * 0.5f * RCP(t);
  bool pos  = (x >= 0.0f);
  float re  = pos ? t : fabsf(q);
  float im  = pos ? q : copysignf(t, y);
  return { re, im };
}

// ---------------------------------------------------------------------------
// Kernel A — wavelength-only (16 blocks), unchanged from R6 (passed).
// Emits float4( n_m.re, n_m.im, z.re, z.im ), z = (n0/n_m)^2.
// ---------------------------------------------------------------------------
__global__ __launch_bounds__(256) void precompute_kernel(
    const float* __restrict__ ri,     // [350]
    const float* __restrict__ fixed,  // [6][3][500]
    const float* __restrict__ wl,     // [4000]
    const int*   __restrict__ md,     // [22]
    float4* __restrict__ nz)          // [7][W]
{
  __shared__ float s_grid[D_];
  __shared__ float s_ri[350];
  __shared__ float s_g[KS_];
  __shared__ float s_mn[4], s_mx[4];

  const int tid = threadIdx.x;

  for (int i = tid; i < D_;  i += 256) s_grid[i] = fixed[i];   // fixed[0][0][:]
  for (int i = tid; i < 350; i += 256) s_ri[i]   = ri[i];
  if (tid < KS_) {
    float x  = -10.0f + (float)tid * (20.0f / 19.0f);
    float xs = x * 0.25f;                         // x / SIGMA
    s_g[tid] = 0.5f * expf(-0.5f * xs * xs);      // unnormalized; scale later
  }

  // block-level min/max of wavelengths (matches jnp.min/jnp.max)
  float lmin = 3.4e38f, lmax = -3.4e38f;
  for (int i = tid; i < W_; i += 256) {
    float v = wl[i];
    lmin = fminf(lmin, v); lmax = fmaxf(lmax, v);
  }
  #pragma unroll
  for (int o = 32; o; o >>= 1) {
    lmin = fminf(lmin, __shfl_xor(lmin, o, 64));
    lmax = fmaxf(lmax, __shfl_xor(lmax, o, 64));
  }
  if ((tid & 63) == 0) { s_mn[tid >> 6] = lmin; s_mx[tid >> 6] = lmax; }
  __syncthreads();
  const float wmin = fminf(fminf(s_mn[0], s_mn[1]), fminf(s_mn[2], s_mn[3]));
  const float wmax = fmaxf(fmaxf(s_mx[0], s_mx[1]), fmaxf(s_mx[2], s_mx[3]));

  const int w  = blockIdx.x * 256 + tid;          // 16*256 = 4096 covers W
  const int wc = min(w, W_ - 1);
  const float x = wl[wc];

  cplx nm[7];   // registers, all indices compile-time

  // fixed materials: searchsorted-right on s_grid
  int lo = 0, hi = D_;
  while (lo < hi) { int mid = (lo + hi) >> 1; if (s_grid[mid] <= x) lo = mid + 1; else hi = mid; }
  const int i = min(max(lo, 1), D_ - 1);
  const float gx0 = s_grid[i - 1];
  const float fr  = (x - gx0) * RCP(s_grid[i] - gx0);
  const bool lowc  = (x < s_grid[0]);
  const bool highc = (x > s_grid[D_ - 1]);

  #pragma unroll
  for (int m = 0; m < 6; ++m) {
    const float* nptr = fixed + (m * 3 + 1) * D_;
    const float* kptr = fixed + (m * 3 + 2) * D_;
    float nv = fmaf(fr, nptr[i] - nptr[i - 1], nptr[i - 1]);
    float kv = fmaf(fr, kptr[i] - kptr[i - 1], kptr[i - 1]);
    if (lowc)  { nv = nptr[0];      kv = kptr[0]; }
    if (highc) { nv = nptr[D_ - 1]; kv = kptr[D_ - 1]; }
    nm[m] = { nv, kv };
  }

  // unknown material: uniform-grid interp of smoothed curve
  {
    float gsum = 0.0f;
    #pragma unroll
    for (int k = 0; k < KS_; ++k) gsum += s_g[k];
    const float ginv  = 1.0f / gsum;
    const float stepd = (wmax - wmin) / (float)(NS_ - 1);
    int j = (int)floorf((x - wmin) * RCP(stepd)) + 1;
    j = min(max(j, 1), NS_ - 1);
    const int j0 = j - 1;
    float a0 = 0.0f, a1 = 0.0f;
    #pragma unroll
    for (int k = 0; k < KS_; ++k) {
      const float gk = s_g[KS_ - 1 - k];
      a0 = fmaf(s_ri[j0 + k], gk, a0);
      a1 = fmaf(s_ri[j0 + 1 + k], gk, a1);
    }
    a0 *= ginv; a1 *= ginv;
    const float d0 = fmaf((float)j0, stepd, wmin);
    const float d1 = fmaf((float)j,  stepd, wmin);
    nm[6] = { fmaf((x - d0) * RCP(d1 - d0), a1 - a0, a0), 0.0f };
  }

  // n0 = n of the incidence material (register select chain, uniform md0)
  const int m0 = md[0];
  cplx n0 = nm[0];
  #pragma unroll
  for (int m = 1; m < 7; ++m) if (m0 == m) n0 = nm[m];

  if (w < W_) {
    #pragma unroll
    for (int m = 0; m < 7; ++m) {
      const cplx q = cmul(n0, cinv(nm[m]));   // n0/n_m
      const cplx z = cmul(q, q);              // (n0/n_m)^2
      nz[m * W_ + w] = make_float4(nm[m].re, nm[m].im, z.re, z.im);
    }
  }
}

// ---------------------------------------------------------------------------
// Kernel B — ratio-form Parratt recursion WITH per-step renormalization.
//   u = N/D;  N' = (beta/s)(r D + N),  D' = (1/s)(D + r N),  s = max(1,|beta|).
// |beta| = e^{-2 di} can be e^{30+} per flipped-evanescent layer (di < 0);
// without the rescale N,D accumulate e^{2 Sum|di|} -> f32 overflow -> the R10
// NaN. With s: every per-step factor has magnitude <= 1 (exp args <= 0), so
// overflow is impossible. Telescoping survives scale-tracking:
//   Pi(1/(1+ru)) = e^{-Sum ls}/D^f, and combined with |e^{i Sum delta}| the
//   tt magnitude exponent is exactly e^{-Sum|di|} (<=1).
// rr = N^f/D^f is scale-invariant. One complex divide total, at the end.
// ---------------------------------------------------------------------------
__global__ __launch_bounds__(256) void tmm_kernel(
    const float4* __restrict__ nz,    // [7][W]
    const float*  __restrict__ wl,    // [4000]
    const float*  __restrict__ ang,   // [64]
    const int*    __restrict__ md,    // [22]
    const float*  __restrict__ tha,   // [10]
    const float*  __restrict__ thb,   // [9]
    const float*  __restrict__ unk,   // [1]
    const float*  __restrict__ comp,  // [1]
    float* __restrict__ out)          // [3][64][4000]
{
  __shared__ float4 s_f[7 * 256];     // (f, 1/f) per material per thread; 28 KB

  const int tid = threadIdx.x;
  const int w = blockIdx.x * 256 + tid;
  if (w >= W_) return;                // safe: kernel has no barriers
  const int a = blockIdx.y;

  const float th0  = ang[a] * (PIF / 180.0f);
  const float s0   = sinf(th0);
  const float s0sq = s0 * s0;
  const float klam = 2.0f * PIF * RCP(wl[w]);

  // f_m = n_m * cos(theta_m),  cos = csqrt(1 - s0^2 * (n0/n_m)^2)
  #pragma unroll
  for (int m = 0; m < 7; ++m) {
    const float4 v = nz[m * W_ + w];
    const cplx st2 = { v.z * s0sq, v.w * s0sq };
    const cplx ct  = csqrtc({ 1.0f - st2.re, -st2.im });
    const cplx f   = cmul({ v.x, v.y }, ct);
    const cplx fi  = cinv(f);
    s_f[m * 256 + tid] = make_float4(f.re, f.im, fi.re, fi.im);
  }

  // renormalized ratio-form backward recursion over interfaces j = 20 .. 1
  cplx N  = { 0.0f, 0.0f };           // u = N / Dn, u_21 = 0
  cplx Dn = { 1.0f, 0.0f };
  cplx Pa = { 1.0f, 0.0f }, Pb = { 1.0f, 0.0f };   // split iop product (ILP)
  float sdr = 0.0f, sabs = 0.0f;      // Sum dr;  Sum |di| (tt magnitude exp)
  float4 fdn = s_f[md[L_ - 1] * 256 + tid];        // f of layer j+1
  const float fL_re = fdn.x;

  #pragma unroll
  for (int j = L_ - 2; j >= 1; --j) {
    const float4 fj = s_f[md[j] * 256 + tid];      // layer j: (f, 1/f)
    // ---- u-independent prep (full ILP across iterations) ----
    const cplx q   = cmul({ fdn.x, fdn.y }, { fj.z, fj.w });   // f_{j+1}/f_j
    const cplx iop = cinv({ 1.0f + q.re, q.im });              // 1/(1+q)
    const cplx r   = cmul({ 1.0f - q.re, -q.im }, iop);        // (1-q)/(1+q)

    const float dthj = (j - 1) < 10 ? tha[j - 1]
                     : ((j - 1) == 10 ? unk[0] / 1000.0f * comp[0]
                                      : thb[j - 12]);
    const float cst = klam * dthj;
    const float dr = fj.x * cst, di = fj.y * cst;  // delta_j
    sdr += dr; sabs += fabsf(di);
    const float em = __expf(-2.0f * fabsf(di));    // <= 1, never overflows
    const bool dpos = (di >= 0.0f);
    const float eN = dpos ? em : 1.0f;             // N factor = |beta|/s
    const float eD = dpos ? 1.0f : em;             // D factor = 1/s
    float sb, cb;
    __sincosf(2.0f * dr, &sb, &cb);
    const cplx pN = { eN * cb, eN * sb };          // (beta/s), |pN| <= 1

    if (j & 1) Pa = cmul(Pa, iop); else Pb = cmul(Pb, iop);

    // ---- serial core: cmul -> add -> cmul / cmul -> add -> scale ----
    const cplx rN = cmul(r, N);
    const cplx rD = cmul(r, Dn);
    N  = cmul(pN, cadd(rD, N));
    Dn = { eD * (Dn.re + rN.re), eD * (Dn.im + rN.im) };

    fdn = fj;
  }

  // interface 0 (fdn == f_1 here; no thickness/scale at this interface)
  const float4 f0v = s_f[md[0] * 256 + tid];
  const cplx q0   = cmul({ fdn.x, fdn.y }, { f0v.z, f0v.w });  // f_1/f_0
  const cplx iop0 = cinv({ 1.0f + q0.re, q0.im });
  const cplx r0   = cmul({ 1.0f - q0.re, -q0.im }, iop0);

  const cplx Nf = cadd(cmul(r0, Dn), N);    // rr = Nf / Df (scale-invariant)
  const cplx Df = cadd(Dn, cmul(r0, N));

  const cplx idf = cinv(Df);
  const cplx rr  = cmul(Nf, idf);

  const float ei = __expf(-sabs);           // e^{-Sum|di|} <= 1
  float ssn, scs;
  __sincosf(sdr, &ssn, &scs);
  const cplx phS = { ei * scs, ei * ssn };

  cplx tt = cmul(cmul(iop0, cmul(cmul(Pa, Pb), phS)), idf);
  const float SCALE = 2097152.0f;           // 2^21 (one 2 per interface)
  tt.re *= SCALE; tt.im *= SCALE;

  const float R = fmaf(rr.re, rr.re, rr.im * rr.im);
  const float T = fmaf(tt.re, tt.re, tt.im * tt.im) * fL_re * RCP(f0v.x);

  const int o = a * W_ + w;
  out[o]               = R;
  out[A_ * W_ + o]     = T;
  out[2 * A_ * W_ + o] = 1.0f - R - T;
}

extern "C" void kernel_launch(void* const* d_in, const int* in_sizes, int n_in,
                              void* d_out, int out_size, void* d_ws, size_t ws_size,
                              hipStream_t stream) {
  const float* ri    = (const float*)d_in[0];
  const float* comp  = (const float*)d_in[1];
  const float* fixed = (const float*)d_in[2];
  const float* tha   = (const float*)d_in[3];
  const float* thb   = (const float*)d_in[4];
  const float* wl    = (const float*)d_in[5];
  const float* ang   = (const float*)d_in[6];
  const int*   md    = (const int*)d_in[7];
  // d_in[8] = polarization (0)
  const float* unk   = (const float*)d_in[9];
  float* out = (float*)d_out;

  float4* nz = (float4*)d_ws;                   // [7][W] = 448 KB

  precompute_kernel<<<16, 256, 0, stream>>>(ri, fixed, wl, md, nz);
  dim3 grid(16, A_);
  tmm_kernel<<<grid, 256, 0, stream>>>(nz, wl, ang, md, tha, thb, unk, comp, out);
}